// Round 6
// baseline (194.539 us; speedup 1.0000x reference)
//
#include <hip/hip_runtime.h>
#include <math.h>

#define EMBED 1024
#define NHEAD 16
#define HDIM 64
#define QKV_LD 3072
// (1/sqrt(64)) * log2(e): softmax scale folded with exp->exp2 conversion
#define SM_SCALE_LOG2 0.18033688f

typedef _Float16 f16x8 __attribute__((ext_vector_type(8)));
typedef float f32x4 __attribute__((ext_vector_type(4)));
typedef unsigned short ushort8v __attribute__((ext_vector_type(8)));
typedef unsigned short ushort4v __attribute__((ext_vector_type(4)));

// async global->LDS, 16B per lane. Dest must be wave-uniform base + lane*16.
__device__ __forceinline__ void gload16(const void* g, void* l) {
    __builtin_amdgcn_global_load_lds(
        (const __attribute__((address_space(1))) unsigned int*)g,
        (__attribute__((address_space(3))) unsigned int*)l, 16, 0, 0);
}

// XCD-aware bijective block swizzle (requires nwg % 8 == 0).
__device__ __forceinline__ int xcd_swz(int bid, int nwg) {
    int cpx = nwg >> 3;
    return (bid & 7) * cpx + (bid >> 3);
}

// XOR-swizzled LDS index (stride 72 ushorts) — attention tiles.
__device__ __forceinline__ int swz(int row, int col) {
    return row * 72 + (col ^ (((row >> 3) & 7) << 3));
}

// ---------------- fp32 -> fp16 convert ----------------
__global__ __launch_bounds__(256) void cvt_f32_f16(
    const float* __restrict__ x, _Float16* __restrict__ y, int n4)
{
    int i = blockIdx.x * 256 + threadIdx.x;
    if (i >= n4) return;
    float4 v = reinterpret_cast<const float4*>(x)[i];
    unsigned short h0 = __builtin_bit_cast(unsigned short, (_Float16)v.x);
    unsigned short h1 = __builtin_bit_cast(unsigned short, (_Float16)v.y);
    unsigned short h2 = __builtin_bit_cast(unsigned short, (_Float16)v.z);
    unsigned short h3 = __builtin_bit_cast(unsigned short, (_Float16)v.w);
    reinterpret_cast<ushort4*>(y)[i] = make_ushort4(h0, h1, h2, h3);
}

// ---------------- fp16 GEMM: 128x128 tile, BK=64, gload_lds staging ----------------
template <bool F16_OUT>
__global__ __launch_bounds__(256) void gemm_m97(
    const _Float16* __restrict__ A, const _Float16* __restrict__ B,
    const float* __restrict__ bias, float* __restrict__ Cf,
    _Float16* __restrict__ Ch, int M, int N, int K, int gx)
{
    __shared__ __align__(16) unsigned short sA[128 * 64];
    __shared__ __align__(16) unsigned short sB[128 * 64];

    const int nwg = gridDim.x;
    const int wgid = xcd_swz(blockIdx.x, nwg);
    const int row0 = (wgid / gx) * 128;
    const int col0 = (wgid % gx) * 128;

    const int tid = threadIdx.x;
    const int lane = tid & 63;
    const int w = tid >> 6;
    const int wr = w >> 1;
    const int wc = w & 1;
    const int c = lane & 15;
    const int g = lane >> 4;

    const unsigned short* Au = (const unsigned short*)A;
    const unsigned short* Bu = (const unsigned short*)B;

    f32x4 acc[4][4];
    #pragma unroll
    for (int m = 0; m < 4; m++)
        #pragma unroll
        for (int n = 0; n < 4; n++)
            acc[m][n] = (f32x4){0.f, 0.f, 0.f, 0.f};

    size_t aoff[4], boff[4];
    int ldst[4];
    #pragma unroll
    for (int i = 0; i < 4; i++) {
        int chunk = (i * 4 + w) * 64 + lane;
        int row = chunk >> 3;
        int scol = ((chunk & 7) ^ (row & 7)) * 8;
        aoff[i] = (size_t)min(row0 + row, M - 1) * K + scol;
        boff[i] = (size_t)min(col0 + row, N - 1) * K + scol;
        ldst[i] = chunk * 8;   // linear LDS dest (ushorts)
    }

    for (int k0 = 0; k0 < K; k0 += 64) {
        __syncthreads();
        #pragma unroll
        for (int i = 0; i < 4; i++) {
            gload16(Au + aoff[i] + k0, &sA[ldst[i]]);
            gload16(Bu + boff[i] + k0, &sB[ldst[i]]);
        }
        __syncthreads();   // compiler emits vmcnt(0) drain

        #pragma unroll
        for (int ks = 0; ks < 2; ks++) {
            f16x8 af[4], bf[4];
            #pragma unroll
            for (int m = 0; m < 4; m++) {
                int row = wr * 64 + m * 16 + c;
                int cc = (ks * 4 + g) ^ (row & 7);
                af[m] = __builtin_bit_cast(f16x8, *reinterpret_cast<const ushort8v*>(
                            &sA[row * 64 + cc * 8]));
            }
            #pragma unroll
            for (int n = 0; n < 4; n++) {
                int row = wc * 64 + n * 16 + c;
                int cc = (ks * 4 + g) ^ (row & 7);
                bf[n] = __builtin_bit_cast(f16x8, *reinterpret_cast<const ushort8v*>(
                            &sB[row * 64 + cc * 8]));
            }
            #pragma unroll
            for (int m = 0; m < 4; m++)
                #pragma unroll
                for (int n = 0; n < 4; n++)
                    acc[m][n] = __builtin_amdgcn_mfma_f32_16x16x32_f16(af[m], bf[n], acc[m][n], 0, 0, 0);
        }
    }

    #pragma unroll
    for (int m = 0; m < 4; m++) {
        #pragma unroll
        for (int n = 0; n < 4; n++) {
            int cc = col0 + wc * 64 + n * 16 + c;
            if (cc >= N) continue;
            float bv = bias[cc];
            #pragma unroll
            for (int j = 0; j < 4; j++) {
                int r = row0 + wr * 64 + m * 16 + g * 4 + j;
                if (r >= M) continue;
                float v = acc[m][n][j] + bv;
                if constexpr (F16_OUT) {
                    Ch[(size_t)r * N + cc] = (_Float16)v;
                } else {
                    Cf[(size_t)r * N + cc] = v;
                }
            }
        }
    }
}

// ---------------- fp16 GEMM: 256x256 tile, BK=64, 8-phase counted-vmcnt ----------------
// T2+T3+T4+T5 per the 256^2 8-phase template. 512 threads = 8 waves (2Mx4N);
// per-wave output 128x64 (acc[8][4]). LDS = 2 buffers x (256x64) x {A,B} =
// 128 KiB (dynamic). Per K-tile: 4 phases (m-quarters); B-frags read once
// (phase 0 of the tile) and held in registers; A-quarter read per phase;
// 16 MFMA per phase. One 128-row stage-unit issued per phase into regions
// whose last ds_read completed >= 2 barriers earlier:
//   p0: A-u1(t+1)->b1 | p1: B-u0(t+2)->b0 | p2: B-u1(t+2)->b0
//   p3: A-u0(t+2)->b0 | p4: A-u1(t+2)->b0 | p5: B-u0(t+3)->b1
//   p6: B-u1(t+3)->b1 | p7: A-u0(t+3)->b1
// vmcnt(6) ONLY before the trailing barriers of p3 and p7 (never 0 in-loop);
// per-thread load counting: every consumed unit is landed at its wait.
// A-unit u = rows {u*64..+64, 128+u*64..+64} (matches m-quarter consumption).
template <bool F16_OUT>
__global__ __launch_bounds__(512, 2) void gemm_256(
    const _Float16* __restrict__ A, const _Float16* __restrict__ B,
    const float* __restrict__ bias, float* __restrict__ Cf,
    _Float16* __restrict__ Ch, int M, int N, int K, int gx)
{
    extern __shared__ __align__(16) unsigned short lds[];
    unsigned short* sA = lds;            // [2][256*64]
    unsigned short* sB = lds + 32768;    // [2][256*64]

    const int nwg = gridDim.x;
    const int wgid = xcd_swz(blockIdx.x, nwg);
    const int row0 = (wgid / gx) * 256;
    const int col0 = (wgid % gx) * 256;

    const int tid = threadIdx.x;
    const int lane = tid & 63;
    const int w = tid >> 6;    // 0..7
    const int wm = w >> 2;     // 0..1
    const int wn = w & 3;      // 0..3
    const int c = lane & 15;
    const int g = lane >> 4;

    const unsigned short* Au = (const unsigned short*)A;
    const unsigned short* Bu = (const unsigned short*)B;

    // staging geometry: unit = 128 rows x 8 chunks(16B); 2 gload16/thread.
    const int rr = tid >> 3;          // 0..63
    const int sc = tid & 7;           // stored chunk
    const int lc = sc ^ (rr & 7);     // logical (global) chunk

    // ds_read chunk per ks (row&7 == c&7 for all fragment rows)
    const int ca0 = (0 + g) ^ (c & 7);
    const int ca1 = (4 + g) ^ (c & 7);

    const int NT = K >> 6;
    const int NITER = NT >> 1;

    f32x4 acc[8][4];
    #pragma unroll
    for (int m = 0; m < 8; m++)
        #pragma unroll
        for (int n = 0; n < 4; n++)
            acc[m][n] = (f32x4){0.f, 0.f, 0.f, 0.f};

    f16x8 af[2][2];
    f16x8 bf[4][2];

#define STG_A(BUF, KT, U) do { \
    int kt_ = (KT) < NT ? (KT) : NT - 1; \
    gload16(Au + (size_t)min(row0 + (U) * 64 + rr, M - 1) * K + kt_ * 64 + lc * 8, \
            &sA[(BUF) * 16384 + ((U) * 64 + rr) * 64 + sc * 8]); \
    gload16(Au + (size_t)min(row0 + (U) * 64 + 128 + rr, M - 1) * K + kt_ * 64 + lc * 8, \
            &sA[(BUF) * 16384 + ((U) * 64 + 128 + rr) * 64 + sc * 8]); \
} while (0)

#define STG_B(BUF, KT, U) do { \
    int kt_ = (KT) < NT ? (KT) : NT - 1; \
    gload16(Bu + (size_t)min(col0 + (U) * 64 + rr, N - 1) * K + kt_ * 64 + lc * 8, \
            &sB[(BUF) * 16384 + ((U) * 64 + rr) * 64 + sc * 8]); \
    gload16(Bu + (size_t)min(col0 + (U) * 64 + 128 + rr, N - 1) * K + kt_ * 64 + lc * 8, \
            &sB[(BUF) * 16384 + ((U) * 64 + 128 + rr) * 64 + sc * 8]); \
} while (0)

#define RD_A(BUF, MQ) do { \
    _Pragma("unroll") \
    for (int m_ = 0; m_ < 2; m_++) { \
        af[m_][0] = __builtin_bit_cast(f16x8, *reinterpret_cast<const ushort8v*>( \
            &sA[(BUF) * 16384 + (wm * 128 + (MQ) * 32 + m_ * 16 + c) * 64 + ca0 * 8])); \
        af[m_][1] = __builtin_bit_cast(f16x8, *reinterpret_cast<const ushort8v*>( \
            &sA[(BUF) * 16384 + (wm * 128 + (MQ) * 32 + m_ * 16 + c) * 64 + ca1 * 8])); \
    } \
} while (0)

#define RD_B(BUF) do { \
    _Pragma("unroll") \
    for (int n_ = 0; n_ < 4; n_++) { \
        bf[n_][0] = __builtin_bit_cast(f16x8, *reinterpret_cast<const ushort8v*>( \
            &sB[(BUF) * 16384 + (wn * 64 + n_ * 16 + c) * 64 + ca0 * 8])); \
        bf[n_][1] = __builtin_bit_cast(f16x8, *reinterpret_cast<const ushort8v*>( \
            &sB[(BUF) * 16384 + (wn * 64 + n_ * 16 + c) * 64 + ca1 * 8])); \
    } \
} while (0)

#define DO_MFMA(MQ) do { \
    __builtin_amdgcn_s_setprio(1); \
    _Pragma("unroll") \
    for (int ks_ = 0; ks_ < 2; ks_++) \
        _Pragma("unroll") \
        for (int m_ = 0; m_ < 2; m_++) \
            _Pragma("unroll") \
            for (int n_ = 0; n_ < 4; n_++) \
                acc[(MQ) * 2 + m_][n_] = __builtin_amdgcn_mfma_f32_16x16x32_f16( \
                    af[m_][ks_], bf[n_][ks_], acc[(MQ) * 2 + m_][n_], 0, 0, 0); \
    __builtin_amdgcn_s_setprio(0); \
} while (0)

#define PH_HEADBAR() do { __builtin_amdgcn_s_barrier(); __builtin_amdgcn_sched_barrier(0); \
    asm volatile("s_waitcnt lgkmcnt(0)" ::: "memory"); __builtin_amdgcn_sched_barrier(0); } while (0)
#define PH_TAILBAR() do { __builtin_amdgcn_s_barrier(); __builtin_amdgcn_sched_barrier(0); } while (0)
#define VM6() do { asm volatile("s_waitcnt vmcnt(6)" ::: "memory"); \
    __builtin_amdgcn_sched_barrier(0); } while (0)

    // Prologue: stage tile0 fully + tile1 {B-u0, B-u1, A-u0}; vmcnt(6) leaves
    // the last 3 units in flight (= steady-state leftover), tile0 landed.
    STG_B(0, 0, 0); STG_B(0, 0, 1); STG_A(0, 0, 0); STG_A(0, 0, 1);
    STG_B(1, 1, 0); STG_B(1, 1, 1); STG_A(1, 1, 0);
    VM6();
    PH_TAILBAR();

    #pragma unroll 1
    for (int i = 0; i < NITER; ++i) {
        const int t1 = 2 * i + 1, t2 = 2 * i + 2, t3 = 2 * i + 3;
        // p0
        RD_B(0); RD_A(0, 0); STG_A(1, t1, 1);
        PH_HEADBAR(); DO_MFMA(0); PH_TAILBAR();
        // p1
        RD_A(0, 1); STG_B(0, t2, 0);
        PH_HEADBAR(); DO_MFMA(1); PH_TAILBAR();
        // p2
        RD_A(0, 2); STG_B(0, t2, 1);
        PH_HEADBAR(); DO_MFMA(2); PH_TAILBAR();
        // p3
        RD_A(0, 3); STG_A(0, t2, 0);
        PH_HEADBAR(); DO_MFMA(3); VM6(); PH_TAILBAR();
        // p4
        RD_B(1); RD_A(1, 0); STG_A(0, t2, 1);
        PH_HEADBAR(); DO_MFMA(0); PH_TAILBAR();
        // p5
        RD_A(1, 1); STG_B(1, t3, 0);
        PH_HEADBAR(); DO_MFMA(1); PH_TAILBAR();
        // p6
        RD_A(1, 2); STG_B(1, t3, 1);
        PH_HEADBAR(); DO_MFMA(2); PH_TAILBAR();
        // p7
        RD_A(1, 3); STG_A(1, t3, 0);
        PH_HEADBAR(); DO_MFMA(3); VM6(); PH_TAILBAR();
    }

    #pragma unroll
    for (int mf = 0; mf < 8; mf++) {
        #pragma unroll
        for (int n = 0; n < 4; n++) {
            int cc2 = col0 + wn * 64 + n * 16 + c;
            if (cc2 >= N) continue;
            float bv = bias[cc2];
            #pragma unroll
            for (int j = 0; j < 4; j++) {
                int r = row0 + wm * 128 + mf * 16 + g * 4 + j;
                if (r >= M) continue;
                float v = acc[mf][n][j] + bv;
                if constexpr (F16_OUT) {
                    Ch[(size_t)r * N + cc2] = (_Float16)v;
                } else {
                    Cf[(size_t)r * N + cc2] = v;
                }
            }
        }
    }

#undef STG_A
#undef STG_B
#undef RD_A
#undef RD_B
#undef DO_MFMA
#undef PH_HEADBAR
#undef PH_TAILBAR
#undef VM6
}

// ---------------- fp16 MFMA varlen attention (swapped QK^T, QBLK=64) ----------------
// r5 state: sP eliminated via matched K-permutation on P(A) and V(B) operands.
__global__ __launch_bounds__(256) void attn_mfma(
    const _Float16* __restrict__ qkv, const int* __restrict__ cu,
    _Float16* __restrict__ ctx, int B, int maxTiles)
{
    __shared__ __align__(16) unsigned short sK[64 * 72];
    __shared__ __align__(16) unsigned short sV[64 * 72];  // V^T: row=d, col=t

    const int nwg = gridDim.x;
    const int wgid = xcd_swz(blockIdx.x, nwg);
    const int h = wgid / maxTiles;
    const int tile = wgid % maxTiles;

    int b = -1, q0 = 0, accum = 0;
    for (int i = 0; i < B; i++) {
        int len = cu[i + 1] - cu[i];
        int nt = (len + 63) >> 6;
        if (tile < accum + nt) { b = i; q0 = (tile - accum) << 6; break; }
        accum += nt;
    }
    if (b < 0) return;
    const int s0 = cu[b];
    const int L = cu[b + 1] - s0;
    if (q0 >= L) return;

    const int tid = threadIdx.x;
    const int lane = tid & 63;
    const int w = tid >> 6;
    const int g = lane >> 4;
    const int c = lane & 15;
    const size_t qcol = (size_t)h * 192;
    const unsigned short* qkvu = (const unsigned short*)qkv;

    f16x8 q[2];
    {
        int qrow = min(q0 + w * 16 + c, L - 1);
        size_t off = (size_t)(s0 + qrow) * QKV_LD + qcol + g * 8;
        q[0] = *reinterpret_cast<const f16x8*>(&qkv[off]);
        q[1] = *reinterpret_cast<const f16x8*>(&qkv[off + 32]);
    }

    f32x4 o[4];
    #pragma unroll
    for (int n = 0; n < 4; n++) o[n] = (f32x4){0.f, 0.f, 0.f, 0.f};
    float m_r = -INFINITY;
    float l_r = 0.f;

    for (int kc = 0; kc < L; kc += 64) {
        __syncthreads();
        #pragma unroll
        for (int it = 0; it < 2; it++) {
            int idx = it * 256 + tid;
            int r = idx >> 3;
            int d0 = (idx & 7) * 8;
            int gr = min(kc + r, L - 1);
            size_t off = (size_t)(s0 + gr) * QKV_LD + qcol + 64 + d0;
            *reinterpret_cast<uint4*>(&sK[swz(r, d0)]) =
                *reinterpret_cast<const uint4*>(&qkvu[off]);
            ushort8v vv = *reinterpret_cast<const ushort8v*>(&qkvu[off + 64]);
            #pragma unroll
            for (int j = 0; j < 8; j++)
                sV[swz(d0 + j, r)] = vv[j];
        }
        __syncthreads();

        __builtin_amdgcn_s_setprio(1);
        f32x4 sacc[4];
        #pragma unroll
        for (int f = 0; f < 4; f++) sacc[f] = (f32x4){0.f, 0.f, 0.f, 0.f};
        #pragma unroll
        for (int f = 0; f < 4; f++) {
            #pragma unroll
            for (int ks = 0; ks < 2; ks++) {
                f16x8 kf = __builtin_bit_cast(f16x8, *reinterpret_cast<const ushort8v*>(
                               &sK[swz(f * 16 + c, ks * 32 + g * 8)]));
                sacc[f] = __builtin_amdgcn_mfma_f32_16x16x32_f16(kf, q[ks], sacc[f], 0, 0, 0);
            }
        }
        __builtin_amdgcn_s_setprio(0);

        float mx = -INFINITY;
        if (kc + 64 <= L) {            // interior tile: no masking needed
            #pragma unroll
            for (int f = 0; f < 4; f++) {
                #pragma unroll
                for (int j = 0; j < 4; j++) {
                    float v = sacc[f][j] * SM_SCALE_LOG2;
                    sacc[f][j] = v;
                    mx = fmaxf(mx, v);
                }
            }
        } else {
            #pragma unroll
            for (int f = 0; f < 4; f++) {
                #pragma unroll
                for (int j = 0; j < 4; j++) {
                    float v = sacc[f][j] * SM_SCALE_LOG2;
                    if (kc + f * 16 + g * 4 + j >= L) v = -1.0e9f;
                    sacc[f][j] = v;
                    mx = fmaxf(mx, v);
                }
            }
        }
        mx = fmaxf(mx, __shfl_xor(mx, 16));
        mx = fmaxf(mx, __shfl_xor(mx, 32));

        // T13 defer-max
        const bool nskip = !__all(mx - m_r <= 8.0f);
        const float mn = nskip ? fmaxf(m_r, mx) : m_r;

        unsigned int paw[4][2];
        float rs = 0.f;
        #pragma unroll
        for (int f = 0; f < 4; f++) {
            float p0 = exp2f(sacc[f][0] - mn);
            float p1 = exp2f(sacc[f][1] - mn);
            float p2 = exp2f(sacc[f][2] - mn);
            float p3 = exp2f(sacc[f][3] - mn);
            rs += (p0 + p1) + (p2 + p3);
            unsigned int h0 = __builtin_bit_cast(unsigned short, (_Float16)p0);
            unsigned int h1 = __builtin_bit_cast(unsigned short, (_Float16)p1);
            unsigned int h2 = __builtin_bit_cast(unsigned short, (_Float16)p2);
            unsigned int h3 = __builtin_bit_cast(unsigned short, (_Float16)p3);
            paw[f][0] = h0 | (h1 << 16);
            paw[f][1] = h2 | (h3 << 16);
        }
        rs += __shfl_xor(rs, 16);
        rs += __shfl_xor(rs, 32);

        if (nskip) {
            float fs = exp2f(m_r - mn);
            l_r = l_r * fs + rs;
            m_r = mn;
            #pragma unroll
            for (int j = 0; j < 4; j++) {
                float fq = __shfl(fs, (lane & 48) | (g * 4 + j));
                #pragma unroll
                for (int n = 0; n < 4; n++)
                    o[n][j] *= fq;
            }
        } else {
            l_r += rs;
        }

        __builtin_amdgcn_s_setprio(1);
        #pragma unroll
        for (int ks = 0; ks < 2; ks++) {
            uint4 pw;
            pw.x = paw[2 * ks][0];
            pw.y = paw[2 * ks][1];
            pw.z = paw[2 * ks + 1][0];
            pw.w = paw[2 * ks + 1][1];
            f16x8 pa = __builtin_bit_cast(f16x8, pw);
            #pragma unroll
            for (int n = 0; n < 4; n++) {
                uint2 lo = *reinterpret_cast<const uint2*>(
                               &sV[swz(n * 16 + c, ks * 32 + g * 4)]);
                uint2 hi = *reinterpret_cast<const uint2*>(
                               &sV[swz(n * 16 + c, ks * 32 + 16 + g * 4)]);
                uint4 vw;
                vw.x = lo.x; vw.y = lo.y; vw.z = hi.x; vw.w = hi.y;
                f16x8 vf = __builtin_bit_cast(f16x8, vw);
                o[n] = __builtin_amdgcn_mfma_f32_16x16x32_f16(pa, vf, o[n], 0, 0, 0);
            }
        }
        __builtin_amdgcn_s_setprio(0);
    }

    float linv[4];
    {
        float il = 1.0f / l_r;
        #pragma unroll
        for (int j = 0; j < 4; j++)
            linv[j] = __shfl(il, (lane & 48) | (g * 4 + j));
    }
    #pragma unroll
    for (int n = 0; n < 4; n++) {
        #pragma unroll
        for (int j = 0; j < 4; j++) {
            int r = q0 + w * 16 + g * 4 + j;
            if (r >= L) continue;
            ctx[(size_t)(s0 + r) * EMBED + h * HDIM + n * 16 + c] =
                (_Float16)(o[n][j] * linv[j]);
        }
    }
}

extern "C" void kernel_launch(void* const* d_in, const int* in_sizes, int n_in,
                              void* d_out, int out_size, void* d_ws, size_t ws_size,
                              hipStream_t stream) {
    const float* hs = (const float*)d_in[0];  // T x 1024
    const float* pw = (const float*)d_in[1];  // 3072 x 1024
    const float* pb = (const float*)d_in[2];  // 3072
    const float* ow = (const float*)d_in[3];  // 1024 x 1024
    const float* ob = (const float*)d_in[4];  // 1024
    const int*   cu = (const int*)d_in[5];    // B+1

    const int T = in_sizes[0] / EMBED;
    const int B = in_sizes[5] - 1;

    char* p = (char*)d_ws;
    size_t hsF_b  = (size_t)T * EMBED * sizeof(_Float16);
    size_t pwF_b  = (size_t)3 * EMBED * EMBED * sizeof(_Float16);
    size_t owF_b  = (size_t)EMBED * EMBED * sizeof(_Float16);
    size_t qkvF_b = (size_t)T * QKV_LD * sizeof(_Float16);
    size_t ctxF_b = hsF_b;

    _Float16* hsF  = (_Float16*)p;  p += hsF_b;
    _Float16* pwF  = (_Float16*)p;  p += pwF_b;
    _Float16* owF  = (_Float16*)p;  p += owF_b;
    _Float16* qkvF = (_Float16*)p;  p += qkvF_b;
    _Float16* ctxF = (_Float16*)p;  p += ctxF_b;

    float* out = (float*)d_out;
    dim3 blk(256);

    // one-time: allow 128 KiB dynamic LDS for the 256^2 GEMM
    static bool attrSet = false;
    if (!attrSet) {
        hipFuncSetAttribute(reinterpret_cast<const void*>(&gemm_256<true>),
                            hipFuncAttributeMaxDynamicSharedMemorySize, 131072);
        attrSet = true;
    }

    // fp32 -> fp16 converts
    {
        int n4 = T * EMBED / 4;
        cvt_f32_f16<<<(n4 + 255) / 256, blk, 0, stream>>>(hs, hsF, n4);
        n4 = 3 * EMBED * EMBED / 4;
        cvt_f32_f16<<<(n4 + 255) / 256, blk, 0, stream>>>(pw, pwF, n4);
        n4 = EMBED * EMBED / 4;
        cvt_f32_f16<<<(n4 + 255) / 256, blk, 0, stream>>>(ow, owF, n4);
    }

    // 1) QKV projection -> fp16 qkv  (256^2 8-phase; gx=12, nwg=288, %8==0)
    {
        int gx = (3 * EMBED) / 256;
        int nwg = gx * ((T + 255) / 256);
        gemm_256<true><<<nwg, dim3(512), 131072, stream>>>(hsF, pwF, pb,
                                                           (float*)nullptr, qkvF,
                                                           T, 3 * EMBED, EMBED, gx);
    }

    // 2) attention -> fp16 ctx  (QBLK=64; nwg = 16 * maxTiles, %8==0)
    {
        int maxTiles = T / 64 + B;
        int nwg = NHEAD * maxTiles;
        attn_mfma<<<nwg, blk, 0, stream>>>(qkvF, cu, ctxF, B, maxTiles);
    }

    // 3) output projection -> fp32 out  (gx=8, nwg=384, %8==0)
    {
        int gx = EMBED / 128;
        int nwg = gx * ((T + 127) / 128);
        gemm_m97<false><<<nwg, blk, 0, stream>>>(ctxF, owF, ob,
                                                 out, (_Float16*)nullptr,
                                                 T, EMBED, EMBED, gx);
    }
}

// Round 7
// 194.026 us; speedup vs baseline: 1.0026x; 1.0026x over previous
//
#include <hip/hip_runtime.h>
#include <math.h>

#define EMBED 1024
#define NHEAD 16
#define HDIM 64
#define QKV_LD 3072
// (1/sqrt(64)) * log2(e): softmax scale folded with exp->exp2 conversion
#define SM_SCALE_LOG2 0.18033688f

typedef _Float16 f16x8 __attribute__((ext_vector_type(8)));
typedef float f32x4 __attribute__((ext_vector_type(4)));
typedef unsigned short ushort8v __attribute__((ext_vector_type(8)));
typedef unsigned short ushort4v __attribute__((ext_vector_type(4)));
typedef unsigned int u32x4 __attribute__((ext_vector_type(4)));

// async global->LDS, 16B per lane. Dest must be wave-uniform base + lane*16.
__device__ __forceinline__ void gload16(const void* g, void* l) {
    __builtin_amdgcn_global_load_lds(
        (const __attribute__((address_space(1))) unsigned int*)g,
        (__attribute__((address_space(3))) unsigned int*)l, 16, 0, 0);
}

// Inline-asm ds_read_b128: invisible to the SIInsertWaitcnts LDS-DMA alias
// tracking, so no compiler-inserted vmcnt(0) drain before LDS reads that
// might alias in-flight global_load_lds destinations. Consumers must be
// fenced by explicit lgkmcnt + sched_barrier (rule #18).
__device__ __forceinline__ f16x8 lds_read_b128(const unsigned short* p) {
    u32x4 r;
    unsigned int a = (unsigned int)(size_t)
        (const __attribute__((address_space(3))) unsigned short*)p;
    asm volatile("ds_read_b128 %0, %1" : "=v"(r) : "v"(a));
    return __builtin_bit_cast(f16x8, r);
}

// XCD-aware bijective block swizzle (requires nwg % 8 == 0).
__device__ __forceinline__ int xcd_swz(int bid, int nwg) {
    int cpx = nwg >> 3;
    return (bid & 7) * cpx + (bid >> 3);
}

// XOR-swizzled LDS index (stride 72 ushorts) — attention tiles.
__device__ __forceinline__ int swz(int row, int col) {
    return row * 72 + (col ^ (((row >> 3) & 7) << 3));
}

// ---------------- fp32 -> fp16 convert ----------------
__global__ __launch_bounds__(256) void cvt_f32_f16(
    const float* __restrict__ x, _Float16* __restrict__ y, int n4)
{
    int i = blockIdx.x * 256 + threadIdx.x;
    if (i >= n4) return;
    float4 v = reinterpret_cast<const float4*>(x)[i];
    unsigned short h0 = __builtin_bit_cast(unsigned short, (_Float16)v.x);
    unsigned short h1 = __builtin_bit_cast(unsigned short, (_Float16)v.y);
    unsigned short h2 = __builtin_bit_cast(unsigned short, (_Float16)v.z);
    unsigned short h3 = __builtin_bit_cast(unsigned short, (_Float16)v.w);
    reinterpret_cast<ushort4*>(y)[i] = make_ushort4(h0, h1, h2, h3);
}

// ---------------- fp16 GEMM: 128x128 tile, BK=64, gload_lds staging ----------------
template <bool F16_OUT>
__global__ __launch_bounds__(256) void gemm_m97(
    const _Float16* __restrict__ A, const _Float16* __restrict__ B,
    const float* __restrict__ bias, float* __restrict__ Cf,
    _Float16* __restrict__ Ch, int M, int N, int K, int gx)
{
    __shared__ __align__(16) unsigned short sA[128 * 64];
    __shared__ __align__(16) unsigned short sB[128 * 64];

    const int nwg = gridDim.x;
    const int wgid = xcd_swz(blockIdx.x, nwg);
    const int row0 = (wgid / gx) * 128;
    const int col0 = (wgid % gx) * 128;

    const int tid = threadIdx.x;
    const int lane = tid & 63;
    const int w = tid >> 6;
    const int wr = w >> 1;
    const int wc = w & 1;
    const int c = lane & 15;
    const int g = lane >> 4;

    const unsigned short* Au = (const unsigned short*)A;
    const unsigned short* Bu = (const unsigned short*)B;

    f32x4 acc[4][4];
    #pragma unroll
    for (int m = 0; m < 4; m++)
        #pragma unroll
        for (int n = 0; n < 4; n++)
            acc[m][n] = (f32x4){0.f, 0.f, 0.f, 0.f};

    size_t aoff[4], boff[4];
    int ldst[4];
    #pragma unroll
    for (int i = 0; i < 4; i++) {
        int chunk = (i * 4 + w) * 64 + lane;
        int row = chunk >> 3;
        int scol = ((chunk & 7) ^ (row & 7)) * 8;
        aoff[i] = (size_t)min(row0 + row, M - 1) * K + scol;
        boff[i] = (size_t)min(col0 + row, N - 1) * K + scol;
        ldst[i] = chunk * 8;   // linear LDS dest (ushorts)
    }

    for (int k0 = 0; k0 < K; k0 += 64) {
        __syncthreads();
        #pragma unroll
        for (int i = 0; i < 4; i++) {
            gload16(Au + aoff[i] + k0, &sA[ldst[i]]);
            gload16(Bu + boff[i] + k0, &sB[ldst[i]]);
        }
        __syncthreads();   // compiler emits vmcnt(0) drain

        #pragma unroll
        for (int ks = 0; ks < 2; ks++) {
            f16x8 af[4], bf[4];
            #pragma unroll
            for (int m = 0; m < 4; m++) {
                int row = wr * 64 + m * 16 + c;
                int cc = (ks * 4 + g) ^ (row & 7);
                af[m] = __builtin_bit_cast(f16x8, *reinterpret_cast<const ushort8v*>(
                            &sA[row * 64 + cc * 8]));
            }
            #pragma unroll
            for (int n = 0; n < 4; n++) {
                int row = wc * 64 + n * 16 + c;
                int cc = (ks * 4 + g) ^ (row & 7);
                bf[n] = __builtin_bit_cast(f16x8, *reinterpret_cast<const ushort8v*>(
                            &sB[row * 64 + cc * 8]));
            }
            #pragma unroll
            for (int m = 0; m < 4; m++)
                #pragma unroll
                for (int n = 0; n < 4; n++)
                    acc[m][n] = __builtin_amdgcn_mfma_f32_16x16x32_f16(af[m], bf[n], acc[m][n], 0, 0, 0);
        }
    }

    #pragma unroll
    for (int m = 0; m < 4; m++) {
        #pragma unroll
        for (int n = 0; n < 4; n++) {
            int cc = col0 + wc * 64 + n * 16 + c;
            if (cc >= N) continue;
            float bv = bias[cc];
            #pragma unroll
            for (int j = 0; j < 4; j++) {
                int r = row0 + wr * 64 + m * 16 + g * 4 + j;
                if (r >= M) continue;
                float v = acc[m][n][j] + bv;
                if constexpr (F16_OUT) {
                    Ch[(size_t)r * N + cc] = (_Float16)v;
                } else {
                    Cf[(size_t)r * N + cc] = v;
                }
            }
        }
    }
}

// ---------------- fp16 GEMM: 256x256 tile, BK=64, 8-phase counted-vmcnt ----------------
// Same schedule as round 6 (stage map, vmcnt(6)@p3/p7 verified by per-thread
// load counting). Round-7 change: asm ds_read_b128 + asm s_barrier so the
// ONLY waitcnts in the loop are the explicit lgkmcnt(0)/vmcnt(6).
template <bool F16_OUT>
__global__ __launch_bounds__(512, 2) void gemm_256(
    const _Float16* __restrict__ A, const _Float16* __restrict__ B,
    const float* __restrict__ bias, float* __restrict__ Cf,
    _Float16* __restrict__ Ch, int M, int N, int K, int gx)
{
    extern __shared__ __align__(16) unsigned short lds[];
    unsigned short* sA = lds;            // [2][256*64]
    unsigned short* sB = lds + 32768;    // [2][256*64]

    const int nwg = gridDim.x;
    const int wgid = xcd_swz(blockIdx.x, nwg);
    const int row0 = (wgid / gx) * 256;
    const int col0 = (wgid % gx) * 256;

    const int tid = threadIdx.x;
    const int lane = tid & 63;
    const int w = tid >> 6;    // 0..7
    const int wm = w >> 2;     // 0..1
    const int wn = w & 3;      // 0..3
    const int c = lane & 15;
    const int g = lane >> 4;

    const unsigned short* Au = (const unsigned short*)A;
    const unsigned short* Bu = (const unsigned short*)B;

    // staging geometry: unit = 128 rows x 8 chunks(16B); 2 gload16/thread.
    const int rr = tid >> 3;          // 0..63
    const int sc = tid & 7;           // stored chunk
    const int lc = sc ^ (rr & 7);     // logical (global) chunk

    // ds_read chunk per ks (row&7 == c&7 for all fragment rows)
    const int ca0 = (0 + g) ^ (c & 7);
    const int ca1 = (4 + g) ^ (c & 7);

    const int NT = K >> 6;
    const int NITER = NT >> 1;

    f32x4 acc[8][4];
    #pragma unroll
    for (int m = 0; m < 8; m++)
        #pragma unroll
        for (int n = 0; n < 4; n++)
            acc[m][n] = (f32x4){0.f, 0.f, 0.f, 0.f};

    f16x8 af[2][2];
    f16x8 bf[4][2];

#define STG_A(BUF, KT, U) do { \
    int kt_ = (KT) < NT ? (KT) : NT - 1; \
    gload16(Au + (size_t)min(row0 + (U) * 64 + rr, M - 1) * K + kt_ * 64 + lc * 8, \
            &sA[(BUF) * 16384 + ((U) * 64 + rr) * 64 + sc * 8]); \
    gload16(Au + (size_t)min(row0 + (U) * 64 + 128 + rr, M - 1) * K + kt_ * 64 + lc * 8, \
            &sA[(BUF) * 16384 + ((U) * 64 + 128 + rr) * 64 + sc * 8]); \
} while (0)

#define STG_B(BUF, KT, U) do { \
    int kt_ = (KT) < NT ? (KT) : NT - 1; \
    gload16(Bu + (size_t)min(col0 + (U) * 64 + rr, N - 1) * K + kt_ * 64 + lc * 8, \
            &sB[(BUF) * 16384 + ((U) * 64 + rr) * 64 + sc * 8]); \
    gload16(Bu + (size_t)min(col0 + (U) * 64 + 128 + rr, N - 1) * K + kt_ * 64 + lc * 8, \
            &sB[(BUF) * 16384 + ((U) * 64 + 128 + rr) * 64 + sc * 8]); \
} while (0)

#define RD_A(BUF, MQ) do { \
    _Pragma("unroll") \
    for (int m_ = 0; m_ < 2; m_++) { \
        af[m_][0] = lds_read_b128( \
            &sA[(BUF) * 16384 + (wm * 128 + (MQ) * 32 + m_ * 16 + c) * 64 + ca0 * 8]); \
        af[m_][1] = lds_read_b128( \
            &sA[(BUF) * 16384 + (wm * 128 + (MQ) * 32 + m_ * 16 + c) * 64 + ca1 * 8]); \
    } \
} while (0)

#define RD_B(BUF) do { \
    _Pragma("unroll") \
    for (int n_ = 0; n_ < 4; n_++) { \
        bf[n_][0] = lds_read_b128( \
            &sB[(BUF) * 16384 + (wn * 64 + n_ * 16 + c) * 64 + ca0 * 8]); \
        bf[n_][1] = lds_read_b128( \
            &sB[(BUF) * 16384 + (wn * 64 + n_ * 16 + c) * 64 + ca1 * 8]); \
    } \
} while (0)

#define DO_MFMA(MQ) do { \
    __builtin_amdgcn_s_setprio(1); \
    _Pragma("unroll") \
    for (int ks_ = 0; ks_ < 2; ks_++) \
        _Pragma("unroll") \
        for (int m_ = 0; m_ < 2; m_++) \
            _Pragma("unroll") \
            for (int n_ = 0; n_ < 4; n_++) \
                acc[(MQ) * 2 + m_][n_] = __builtin_amdgcn_mfma_f32_16x16x32_f16( \
                    af[m_][ks_], bf[n_][ks_], acc[(MQ) * 2 + m_][n_], 0, 0, 0); \
    __builtin_amdgcn_s_setprio(0); \
} while (0)

#define BAR() do { __builtin_amdgcn_sched_barrier(0); \
    asm volatile("s_barrier" ::: "memory"); \
    __builtin_amdgcn_sched_barrier(0); } while (0)
#define PH_HEADBAR() do { BAR(); \
    asm volatile("s_waitcnt lgkmcnt(0)" ::: "memory"); \
    __builtin_amdgcn_sched_barrier(0); } while (0)
#define PH_TAILBAR() BAR()
#define VM6() do { asm volatile("s_waitcnt vmcnt(6)" ::: "memory"); \
    __builtin_amdgcn_sched_barrier(0); } while (0)

    // Prologue: stage tile0 fully + tile1 {B-u0, B-u1, A-u0}; vmcnt(6) leaves
    // the last 3 units in flight (= steady-state leftover), tile0 landed.
    STG_B(0, 0, 0); STG_B(0, 0, 1); STG_A(0, 0, 0); STG_A(0, 0, 1);
    STG_B(1, 1, 0); STG_B(1, 1, 1); STG_A(1, 1, 0);
    VM6();
    PH_TAILBAR();

    #pragma unroll 1
    for (int i = 0; i < NITER; ++i) {
        const int t1 = 2 * i + 1, t2 = 2 * i + 2, t3 = 2 * i + 3;
        // p0
        RD_B(0); RD_A(0, 0); STG_A(1, t1, 1);
        PH_HEADBAR(); DO_MFMA(0); PH_TAILBAR();
        // p1
        RD_A(0, 1); STG_B(0, t2, 0);
        PH_HEADBAR(); DO_MFMA(1); PH_TAILBAR();
        // p2
        RD_A(0, 2); STG_B(0, t2, 1);
        PH_HEADBAR(); DO_MFMA(2); PH_TAILBAR();
        // p3
        RD_A(0, 3); STG_A(0, t2, 0);
        PH_HEADBAR(); DO_MFMA(3); VM6(); PH_TAILBAR();
        // p4
        RD_B(1); RD_A(1, 0); STG_A(0, t2, 1);
        PH_HEADBAR(); DO_MFMA(0); PH_TAILBAR();
        // p5
        RD_A(1, 1); STG_B(1, t3, 0);
        PH_HEADBAR(); DO_MFMA(1); PH_TAILBAR();
        // p6
        RD_A(1, 2); STG_B(1, t3, 1);
        PH_HEADBAR(); DO_MFMA(2); PH_TAILBAR();
        // p7
        RD_A(1, 3); STG_A(1, t3, 0);
        PH_HEADBAR(); DO_MFMA(3); VM6(); PH_TAILBAR();
    }

    #pragma unroll
    for (int mf = 0; mf < 8; mf++) {
        #pragma unroll
        for (int n = 0; n < 4; n++) {
            int cc2 = col0 + wn * 64 + n * 16 + c;
            if (cc2 >= N) continue;
            float bv = bias[cc2];
            #pragma unroll
            for (int j = 0; j < 4; j++) {
                int r = row0 + wm * 128 + mf * 16 + g * 4 + j;
                if (r >= M) continue;
                float v = acc[mf][n][j] + bv;
                if constexpr (F16_OUT) {
                    Ch[(size_t)r * N + cc2] = (_Float16)v;
                } else {
                    Cf[(size_t)r * N + cc2] = v;
                }
            }
        }
    }

#undef STG_A
#undef STG_B
#undef RD_A
#undef RD_B
#undef DO_MFMA
#undef BAR
#undef PH_HEADBAR
#undef PH_TAILBAR
#undef VM6
}

// ---------------- fp16 MFMA varlen attention (swapped QK^T, QBLK=64) ----------------
// r5 state: sP eliminated via matched K-permutation on P(A) and V(B) operands.
__global__ __launch_bounds__(256) void attn_mfma(
    const _Float16* __restrict__ qkv, const int* __restrict__ cu,
    _Float16* __restrict__ ctx, int B, int maxTiles)
{
    __shared__ __align__(16) unsigned short sK[64 * 72];
    __shared__ __align__(16) unsigned short sV[64 * 72];  // V^T: row=d, col=t

    const int nwg = gridDim.x;
    const int wgid = xcd_swz(blockIdx.x, nwg);
    const int h = wgid / maxTiles;
    const int tile = wgid % maxTiles;

    int b = -1, q0 = 0, accum = 0;
    for (int i = 0; i < B; i++) {
        int len = cu[i + 1] - cu[i];
        int nt = (len + 63) >> 6;
        if (tile < accum + nt) { b = i; q0 = (tile - accum) << 6; break; }
        accum += nt;
    }
    if (b < 0) return;
    const int s0 = cu[b];
    const int L = cu[b + 1] - s0;
    if (q0 >= L) return;

    const int tid = threadIdx.x;
    const int lane = tid & 63;
    const int w = tid >> 6;
    const int g = lane >> 4;
    const int c = lane & 15;
    const size_t qcol = (size_t)h * 192;
    const unsigned short* qkvu = (const unsigned short*)qkv;

    f16x8 q[2];
    {
        int qrow = min(q0 + w * 16 + c, L - 1);
        size_t off = (size_t)(s0 + qrow) * QKV_LD + qcol + g * 8;
        q[0] = *reinterpret_cast<const f16x8*>(&qkv[off]);
        q[1] = *reinterpret_cast<const f16x8*>(&qkv[off + 32]);
    }

    f32x4 o[4];
    #pragma unroll
    for (int n = 0; n < 4; n++) o[n] = (f32x4){0.f, 0.f, 0.f, 0.f};
    float m_r = -INFINITY;
    float l_r = 0.f;

    for (int kc = 0; kc < L; kc += 64) {
        __syncthreads();
        #pragma unroll
        for (int it = 0; it < 2; it++) {
            int idx = it * 256 + tid;
            int r = idx >> 3;
            int d0 = (idx & 7) * 8;
            int gr = min(kc + r, L - 1);
            size_t off = (size_t)(s0 + gr) * QKV_LD + qcol + 64 + d0;
            *reinterpret_cast<uint4*>(&sK[swz(r, d0)]) =
                *reinterpret_cast<const uint4*>(&qkvu[off]);
            ushort8v vv = *reinterpret_cast<const ushort8v*>(&qkvu[off + 64]);
            #pragma unroll
            for (int j = 0; j < 8; j++)
                sV[swz(d0 + j, r)] = vv[j];
        }
        __syncthreads();

        __builtin_amdgcn_s_setprio(1);
        f32x4 sacc[4];
        #pragma unroll
        for (int f = 0; f < 4; f++) sacc[f] = (f32x4){0.f, 0.f, 0.f, 0.f};
        #pragma unroll
        for (int f = 0; f < 4; f++) {
            #pragma unroll
            for (int ks = 0; ks < 2; ks++) {
                f16x8 kf = __builtin_bit_cast(f16x8, *reinterpret_cast<const ushort8v*>(
                               &sK[swz(f * 16 + c, ks * 32 + g * 8)]));
                sacc[f] = __builtin_amdgcn_mfma_f32_16x16x32_f16(kf, q[ks], sacc[f], 0, 0, 0);
            }
        }
        __builtin_amdgcn_s_setprio(0);

        float mx = -INFINITY;
        if (kc + 64 <= L) {            // interior tile: no masking needed
            #pragma unroll
            for (int f = 0; f < 4; f++) {
                #pragma unroll
                for (int j = 0; j < 4; j++) {
                    float v = sacc[f][j] * SM_SCALE_LOG2;
                    sacc[f][j] = v;
                    mx = fmaxf(mx, v);
                }
            }
        } else {
            #pragma unroll
            for (int f = 0; f < 4; f++) {
                #pragma unroll
                for (int j = 0; j < 4; j++) {
                    float v = sacc[f][j] * SM_SCALE_LOG2;
                    if (kc + f * 16 + g * 4 + j >= L) v = -1.0e9f;
                    sacc[f][j] = v;
                    mx = fmaxf(mx, v);
                }
            }
        }
        mx = fmaxf(mx, __shfl_xor(mx, 16));
        mx = fmaxf(mx, __shfl_xor(mx, 32));

        // T13 defer-max
        const bool nskip = !__all(mx - m_r <= 8.0f);
        const float mn = nskip ? fmaxf(m_r, mx) : m_r;

        unsigned int paw[4][2];
        float rs = 0.f;
        #pragma unroll
        for (int f = 0; f < 4; f++) {
            float p0 = exp2f(sacc[f][0] - mn);
            float p1 = exp2f(sacc[f][1] - mn);
            float p2 = exp2f(sacc[f][2] - mn);
            float p3 = exp2f(sacc[f][3] - mn);
            rs += (p0 + p1) + (p2 + p3);
            unsigned int h0 = __builtin_bit_cast(unsigned short, (_Float16)p0);
            unsigned int h1 = __builtin_bit_cast(unsigned short, (_Float16)p1);
            unsigned int h2 = __builtin_bit_cast(unsigned short, (_Float16)p2);
            unsigned int h3 = __builtin_bit_cast(unsigned short, (_Float16)p3);
            paw[f][0] = h0 | (h1 << 16);
            paw[f][1] = h2 | (h3 << 16);
        }
        rs += __shfl_xor(rs, 16);
        rs += __shfl_xor(rs, 32);

        if (nskip) {
            float fs = exp2f(m_r - mn);
            l_r = l_r * fs + rs;
            m_r = mn;
            #pragma unroll
            for (int j = 0; j < 4; j++) {
                float fq = __shfl(fs, (lane & 48) | (g * 4 + j));
                #pragma unroll
                for (int n = 0; n < 4; n++)
                    o[n][j] *= fq;
            }
        } else {
            l_r += rs;
        }

        __builtin_amdgcn_s_setprio(1);
        #pragma unroll
        for (int ks = 0; ks < 2; ks++) {
            uint4 pw;
            pw.x = paw[2 * ks][0];
            pw.y = paw[2 * ks][1];
            pw.z = paw[2 * ks + 1][0];
            pw.w = paw[2 * ks + 1][1];
            f16x8 pa = __builtin_bit_cast(f16x8, pw);
            #pragma unroll
            for (int n = 0; n < 4; n++) {
                uint2 lo = *reinterpret_cast<const uint2*>(
                               &sV[swz(n * 16 + c, ks * 32 + g * 4)]);
                uint2 hi = *reinterpret_cast<const uint2*>(
                               &sV[swz(n * 16 + c, ks * 32 + 16 + g * 4)]);
                uint4 vw;
                vw.x = lo.x; vw.y = lo.y; vw.z = hi.x; vw.w = hi.y;
                f16x8 vf = __builtin_bit_cast(f16x8, vw);
                o[n] = __builtin_amdgcn_mfma_f32_16x16x32_f16(pa, vf, o[n], 0, 0, 0);
            }
        }
        __builtin_amdgcn_s_setprio(0);
    }

    float linv[4];
    {
        float il = 1.0f / l_r;
        #pragma unroll
        for (int j = 0; j < 4; j++)
            linv[j] = __shfl(il, (lane & 48) | (g * 4 + j));
    }
    #pragma unroll
    for (int n = 0; n < 4; n++) {
        #pragma unroll
        for (int j = 0; j < 4; j++) {
            int r = q0 + w * 16 + g * 4 + j;
            if (r >= L) continue;
            ctx[(size_t)(s0 + r) * EMBED + h * HDIM + n * 16 + c] =
                (_Float16)(o[n][j] * linv[j]);
        }
    }
}

extern "C" void kernel_launch(void* const* d_in, const int* in_sizes, int n_in,
                              void* d_out, int out_size, void* d_ws, size_t ws_size,
                              hipStream_t stream) {
    const float* hs = (const float*)d_in[0];  // T x 1024
    const float* pw = (const float*)d_in[1];  // 3072 x 1024
    const float* pb = (const float*)d_in[2];  // 3072
    const float* ow = (const float*)d_in[3];  // 1024 x 1024
    const float* ob = (const float*)d_in[4];  // 1024
    const int*   cu = (const int*)d_in[5];    // B+1

    const int T = in_sizes[0] / EMBED;
    const int B = in_sizes[5] - 1;

    char* p = (char*)d_ws;
    size_t hsF_b  = (size_t)T * EMBED * sizeof(_Float16);
    size_t pwF_b  = (size_t)3 * EMBED * EMBED * sizeof(_Float16);
    size_t owF_b  = (size_t)EMBED * EMBED * sizeof(_Float16);
    size_t qkvF_b = (size_t)T * QKV_LD * sizeof(_Float16);
    size_t ctxF_b = hsF_b;

    _Float16* hsF  = (_Float16*)p;  p += hsF_b;
    _Float16* pwF  = (_Float16*)p;  p += pwF_b;
    _Float16* owF  = (_Float16*)p;  p += owF_b;
    _Float16* qkvF = (_Float16*)p;  p += qkvF_b;
    _Float16* ctxF = (_Float16*)p;  p += ctxF_b;

    float* out = (float*)d_out;
    dim3 blk(256);

    // one-time: allow 128 KiB dynamic LDS for the 256^2 GEMM
    static bool attrSet = false;
    if (!attrSet) {
        hipFuncSetAttribute(reinterpret_cast<const void*>(&gemm_256<true>),
                            hipFuncAttributeMaxDynamicSharedMemorySize, 131072);
        attrSet = true;
    }

    // fp32 -> fp16 converts
    {
        int n4 = T * EMBED / 4;
        cvt_f32_f16<<<(n4 + 255) / 256, blk, 0, stream>>>(hs, hsF, n4);
        n4 = 3 * EMBED * EMBED / 4;
        cvt_f32_f16<<<(n4 + 255) / 256, blk, 0, stream>>>(pw, pwF, n4);
        n4 = EMBED * EMBED / 4;
        cvt_f32_f16<<<(n4 + 255) / 256, blk, 0, stream>>>(ow, owF, n4);
    }

    // 1) QKV projection -> fp16 qkv  (256^2 8-phase; gx=12, nwg=288, %8==0)
    {
        int gx = (3 * EMBED) / 256;
        int nwg = gx * ((T + 255) / 256);
        gemm_256<true><<<nwg, dim3(512), 131072, stream>>>(hsF, pwF, pb,
                                                           (float*)nullptr, qkvF,
                                                           T, 3 * EMBED, EMBED, gx);
    }

    // 2) attention -> fp16 ctx  (QBLK=64; nwg = 16 * maxTiles, %8==0)
    {
        int maxTiles = T / 64 + B;
        int nwg = NHEAD * maxTiles;
        attn_mfma<<<nwg, blk, 0, stream>>>(qkvF, cu, ctxF, B, maxTiles);
    }

    // 3) output projection -> fp32 out  (gx=8, nwg=384, %8==0)
    {
        int gx = EMBED / 128;
        int nwg = gx * ((T + 127) / 128);
        gemm_m97<false><<<nwg, blk, 0, stream>>>(ctxF, owF, ob,
                                                 out, (_Float16*)nullptr,
                                                 T, EMBED, EMBED, gx);
    }
}

// Round 8
// 172.811 us; speedup vs baseline: 1.1257x; 1.1228x over previous
//
#include <hip/hip_runtime.h>
#include <math.h>

#define EMBED 1024
#define NHEAD 16
#define HDIM 64
#define QKV_LD 3072
// (1/sqrt(64)) * log2(e): softmax scale folded with exp->exp2 conversion
#define SM_SCALE_LOG2 0.18033688f

typedef _Float16 f16x8 __attribute__((ext_vector_type(8)));
typedef float f32x4 __attribute__((ext_vector_type(4)));
typedef unsigned short ushort8v __attribute__((ext_vector_type(8)));
typedef unsigned short ushort4v __attribute__((ext_vector_type(4)));

// async global->LDS, 16B per lane. Dest must be wave-uniform base + lane*16.
__device__ __forceinline__ void gload16(const void* g, void* l) {
    __builtin_amdgcn_global_load_lds(
        (const __attribute__((address_space(1))) unsigned int*)g,
        (__attribute__((address_space(3))) unsigned int*)l, 16, 0, 0);
}

// XCD-aware bijective block swizzle (requires nwg % 8 == 0).
__device__ __forceinline__ int xcd_swz(int bid, int nwg) {
    int cpx = nwg >> 3;
    return (bid & 7) * cpx + (bid >> 3);
}

// XOR-swizzled LDS index (stride 72 ushorts) — attention tiles.
__device__ __forceinline__ int swz(int row, int col) {
    return row * 72 + (col ^ (((row >> 3) & 7) << 3));
}

// ---------------- fused fp32 -> fp16 convert (3 tensors, 1 launch) ----------------
// Regions: [0, nA) -> hs->hsF ; [nA, nA+nB) -> pw->pwF ; [nA+nB, nA+nB+nC) -> ow->owF
__global__ __launch_bounds__(256) void cvt3_f32_f16(
    const float* __restrict__ xa, _Float16* __restrict__ ya, int nA,
    const float* __restrict__ xb, _Float16* __restrict__ yb, int nB,
    const float* __restrict__ xc, _Float16* __restrict__ yc, int nC)
{
    int i = blockIdx.x * 256 + threadIdx.x;
    const float* x;
    _Float16* y;
    if (i < nA)               { x = xa; y = ya; }
    else if (i < nA + nB)     { x = xb; y = yb; i -= nA; }
    else if (i < nA + nB + nC){ x = xc; y = yc; i -= nA + nB; }
    else return;
    float4 v = reinterpret_cast<const float4*>(x)[i];
    unsigned short h0 = __builtin_bit_cast(unsigned short, (_Float16)v.x);
    unsigned short h1 = __builtin_bit_cast(unsigned short, (_Float16)v.y);
    unsigned short h2 = __builtin_bit_cast(unsigned short, (_Float16)v.z);
    unsigned short h3 = __builtin_bit_cast(unsigned short, (_Float16)v.w);
    reinterpret_cast<ushort4*>(y)[i] = make_ushort4(h0, h1, h2, h3);
}

// ---------------- fp16 GEMM: 128x128 tile, BK=64, gload_lds staging ----------------
template <bool F16_OUT>
__global__ __launch_bounds__(256) void gemm_m97(
    const _Float16* __restrict__ A, const _Float16* __restrict__ B,
    const float* __restrict__ bias, float* __restrict__ Cf,
    _Float16* __restrict__ Ch, int M, int N, int K, int gx)
{
    __shared__ __align__(16) unsigned short sA[128 * 64];
    __shared__ __align__(16) unsigned short sB[128 * 64];

    const int nwg = gridDim.x;
    const int wgid = xcd_swz(blockIdx.x, nwg);
    const int row0 = (wgid / gx) * 128;
    const int col0 = (wgid % gx) * 128;

    const int tid = threadIdx.x;
    const int lane = tid & 63;
    const int w = tid >> 6;
    const int wr = w >> 1;
    const int wc = w & 1;
    const int c = lane & 15;
    const int g = lane >> 4;

    const unsigned short* Au = (const unsigned short*)A;
    const unsigned short* Bu = (const unsigned short*)B;

    f32x4 acc[4][4];
    #pragma unroll
    for (int m = 0; m < 4; m++)
        #pragma unroll
        for (int n = 0; n < 4; n++)
            acc[m][n] = (f32x4){0.f, 0.f, 0.f, 0.f};

    size_t aoff[4], boff[4];
    int ldst[4];
    #pragma unroll
    for (int i = 0; i < 4; i++) {
        int chunk = (i * 4 + w) * 64 + lane;
        int row = chunk >> 3;
        int scol = ((chunk & 7) ^ (row & 7)) * 8;
        aoff[i] = (size_t)min(row0 + row, M - 1) * K + scol;
        boff[i] = (size_t)min(col0 + row, N - 1) * K + scol;
        ldst[i] = chunk * 8;   // linear LDS dest (ushorts)
    }

    for (int k0 = 0; k0 < K; k0 += 64) {
        __syncthreads();
        #pragma unroll
        for (int i = 0; i < 4; i++) {
            gload16(Au + aoff[i] + k0, &sA[ldst[i]]);
            gload16(Bu + boff[i] + k0, &sB[ldst[i]]);
        }
        __syncthreads();   // compiler emits vmcnt(0) drain

        #pragma unroll
        for (int ks = 0; ks < 2; ks++) {
            f16x8 af[4], bf[4];
            #pragma unroll
            for (int m = 0; m < 4; m++) {
                int row = wr * 64 + m * 16 + c;
                int cc = (ks * 4 + g) ^ (row & 7);
                af[m] = __builtin_bit_cast(f16x8, *reinterpret_cast<const ushort8v*>(
                            &sA[row * 64 + cc * 8]));
            }
            #pragma unroll
            for (int n = 0; n < 4; n++) {
                int row = wc * 64 + n * 16 + c;
                int cc = (ks * 4 + g) ^ (row & 7);
                bf[n] = __builtin_bit_cast(f16x8, *reinterpret_cast<const ushort8v*>(
                            &sB[row * 64 + cc * 8]));
            }
            #pragma unroll
            for (int m = 0; m < 4; m++)
                #pragma unroll
                for (int n = 0; n < 4; n++)
                    acc[m][n] = __builtin_amdgcn_mfma_f32_16x16x32_f16(af[m], bf[n], acc[m][n], 0, 0, 0);
        }
    }

    #pragma unroll
    for (int m = 0; m < 4; m++) {
        #pragma unroll
        for (int n = 0; n < 4; n++) {
            int cc = col0 + wc * 64 + n * 16 + c;
            if (cc >= N) continue;
            float bv = bias[cc];
            #pragma unroll
            for (int j = 0; j < 4; j++) {
                int r = row0 + wr * 64 + m * 16 + g * 4 + j;
                if (r >= M) continue;
                float v = acc[m][n][j] + bv;
                if constexpr (F16_OUT) {
                    Ch[(size_t)r * N + cc] = (_Float16)v;
                } else {
                    Cf[(size_t)r * N + cc] = v;
                }
            }
        }
    }
}

// ---------------- fp16 MFMA varlen attention (swapped QK^T, QBLK=64) ----------------
// r5 state: sP eliminated via matched K-permutation on P(A) and V(B) operands.
__global__ __launch_bounds__(256) void attn_mfma(
    const _Float16* __restrict__ qkv, const int* __restrict__ cu,
    _Float16* __restrict__ ctx, int B, int maxTiles)
{
    __shared__ __align__(16) unsigned short sK[64 * 72];
    __shared__ __align__(16) unsigned short sV[64 * 72];  // V^T: row=d, col=t

    const int nwg = gridDim.x;
    const int wgid = xcd_swz(blockIdx.x, nwg);
    const int h = wgid / maxTiles;
    const int tile = wgid % maxTiles;

    int b = -1, q0 = 0, accum = 0;
    for (int i = 0; i < B; i++) {
        int len = cu[i + 1] - cu[i];
        int nt = (len + 63) >> 6;
        if (tile < accum + nt) { b = i; q0 = (tile - accum) << 6; break; }
        accum += nt;
    }
    if (b < 0) return;
    const int s0 = cu[b];
    const int L = cu[b + 1] - s0;
    if (q0 >= L) return;

    const int tid = threadIdx.x;
    const int lane = tid & 63;
    const int w = tid >> 6;
    const int g = lane >> 4;
    const int c = lane & 15;
    const size_t qcol = (size_t)h * 192;
    const unsigned short* qkvu = (const unsigned short*)qkv;

    f16x8 q[2];
    {
        int qrow = min(q0 + w * 16 + c, L - 1);
        size_t off = (size_t)(s0 + qrow) * QKV_LD + qcol + g * 8;
        q[0] = *reinterpret_cast<const f16x8*>(&qkv[off]);
        q[1] = *reinterpret_cast<const f16x8*>(&qkv[off + 32]);
    }

    f32x4 o[4];
    #pragma unroll
    for (int n = 0; n < 4; n++) o[n] = (f32x4){0.f, 0.f, 0.f, 0.f};
    float m_r = -INFINITY;
    float l_r = 0.f;

    for (int kc = 0; kc < L; kc += 64) {
        __syncthreads();
        #pragma unroll
        for (int it = 0; it < 2; it++) {
            int idx = it * 256 + tid;
            int r = idx >> 3;
            int d0 = (idx & 7) * 8;
            int gr = min(kc + r, L - 1);
            size_t off = (size_t)(s0 + gr) * QKV_LD + qcol + 64 + d0;
            *reinterpret_cast<uint4*>(&sK[swz(r, d0)]) =
                *reinterpret_cast<const uint4*>(&qkvu[off]);
            ushort8v vv = *reinterpret_cast<const ushort8v*>(&qkvu[off + 64]);
            #pragma unroll
            for (int j = 0; j < 8; j++)
                sV[swz(d0 + j, r)] = vv[j];
        }
        __syncthreads();

        __builtin_amdgcn_s_setprio(1);
        f32x4 sacc[4];
        #pragma unroll
        for (int f = 0; f < 4; f++) sacc[f] = (f32x4){0.f, 0.f, 0.f, 0.f};
        #pragma unroll
        for (int f = 0; f < 4; f++) {
            #pragma unroll
            for (int ks = 0; ks < 2; ks++) {
                f16x8 kf = __builtin_bit_cast(f16x8, *reinterpret_cast<const ushort8v*>(
                               &sK[swz(f * 16 + c, ks * 32 + g * 8)]));
                sacc[f] = __builtin_amdgcn_mfma_f32_16x16x32_f16(kf, q[ks], sacc[f], 0, 0, 0);
            }
        }
        __builtin_amdgcn_s_setprio(0);

        float mx = -INFINITY;
        if (kc + 64 <= L) {            // interior tile: no masking needed
            #pragma unroll
            for (int f = 0; f < 4; f++) {
                #pragma unroll
                for (int j = 0; j < 4; j++) {
                    float v = sacc[f][j] * SM_SCALE_LOG2;
                    sacc[f][j] = v;
                    mx = fmaxf(mx, v);
                }
            }
        } else {
            #pragma unroll
            for (int f = 0; f < 4; f++) {
                #pragma unroll
                for (int j = 0; j < 4; j++) {
                    float v = sacc[f][j] * SM_SCALE_LOG2;
                    if (kc + f * 16 + g * 4 + j >= L) v = -1.0e9f;
                    sacc[f][j] = v;
                    mx = fmaxf(mx, v);
                }
            }
        }
        mx = fmaxf(mx, __shfl_xor(mx, 16));
        mx = fmaxf(mx, __shfl_xor(mx, 32));

        // T13 defer-max
        const bool nskip = !__all(mx - m_r <= 8.0f);
        const float mn = nskip ? fmaxf(m_r, mx) : m_r;

        unsigned int paw[4][2];
        float rs = 0.f;
        #pragma unroll
        for (int f = 0; f < 4; f++) {
            float p0 = exp2f(sacc[f][0] - mn);
            float p1 = exp2f(sacc[f][1] - mn);
            float p2 = exp2f(sacc[f][2] - mn);
            float p3 = exp2f(sacc[f][3] - mn);
            rs += (p0 + p1) + (p2 + p3);
            unsigned int h0 = __builtin_bit_cast(unsigned short, (_Float16)p0);
            unsigned int h1 = __builtin_bit_cast(unsigned short, (_Float16)p1);
            unsigned int h2 = __builtin_bit_cast(unsigned short, (_Float16)p2);
            unsigned int h3 = __builtin_bit_cast(unsigned short, (_Float16)p3);
            paw[f][0] = h0 | (h1 << 16);
            paw[f][1] = h2 | (h3 << 16);
        }
        rs += __shfl_xor(rs, 16);
        rs += __shfl_xor(rs, 32);

        if (nskip) {
            float fs = exp2f(m_r - mn);
            l_r = l_r * fs + rs;
            m_r = mn;
            #pragma unroll
            for (int j = 0; j < 4; j++) {
                float fq = __shfl(fs, (lane & 48) | (g * 4 + j));
                #pragma unroll
                for (int n = 0; n < 4; n++)
                    o[n][j] *= fq;
            }
        } else {
            l_r += rs;
        }

        __builtin_amdgcn_s_setprio(1);
        #pragma unroll
        for (int ks = 0; ks < 2; ks++) {
            uint4 pw;
            pw.x = paw[2 * ks][0];
            pw.y = paw[2 * ks][1];
            pw.z = paw[2 * ks + 1][0];
            pw.w = paw[2 * ks + 1][1];
            f16x8 pa = __builtin_bit_cast(f16x8, pw);
            #pragma unroll
            for (int n = 0; n < 4; n++) {
                uint2 lo = *reinterpret_cast<const uint2*>(
                               &sV[swz(n * 16 + c, ks * 32 + g * 4)]);
                uint2 hi = *reinterpret_cast<const uint2*>(
                               &sV[swz(n * 16 + c, ks * 32 + 16 + g * 4)]);
                uint4 vw;
                vw.x = lo.x; vw.y = lo.y; vw.z = hi.x; vw.w = hi.y;
                f16x8 vf = __builtin_bit_cast(f16x8, vw);
                o[n] = __builtin_amdgcn_mfma_f32_16x16x32_f16(pa, vf, o[n], 0, 0, 0);
            }
        }
        __builtin_amdgcn_s_setprio(0);
    }

    float linv[4];
    {
        float il = 1.0f / l_r;
        #pragma unroll
        for (int j = 0; j < 4; j++)
            linv[j] = __shfl(il, (lane & 48) | (g * 4 + j));
    }
    #pragma unroll
    for (int n = 0; n < 4; n++) {
        #pragma unroll
        for (int j = 0; j < 4; j++) {
            int r = q0 + w * 16 + g * 4 + j;
            if (r >= L) continue;
            ctx[(size_t)(s0 + r) * EMBED + h * HDIM + n * 16 + c] =
                (_Float16)(o[n][j] * linv[j]);
        }
    }
}

extern "C" void kernel_launch(void* const* d_in, const int* in_sizes, int n_in,
                              void* d_out, int out_size, void* d_ws, size_t ws_size,
                              hipStream_t stream) {
    const float* hs = (const float*)d_in[0];  // T x 1024
    const float* pw = (const float*)d_in[1];  // 3072 x 1024
    const float* pb = (const float*)d_in[2];  // 3072
    const float* ow = (const float*)d_in[3];  // 1024 x 1024
    const float* ob = (const float*)d_in[4];  // 1024
    const int*   cu = (const int*)d_in[5];    // B+1

    const int T = in_sizes[0] / EMBED;
    const int B = in_sizes[5] - 1;

    char* p = (char*)d_ws;
    size_t hsF_b  = (size_t)T * EMBED * sizeof(_Float16);
    size_t pwF_b  = (size_t)3 * EMBED * EMBED * sizeof(_Float16);
    size_t owF_b  = (size_t)EMBED * EMBED * sizeof(_Float16);
    size_t qkvF_b = (size_t)T * QKV_LD * sizeof(_Float16);
    size_t ctxF_b = hsF_b;

    _Float16* hsF  = (_Float16*)p;  p += hsF_b;
    _Float16* pwF  = (_Float16*)p;  p += pwF_b;
    _Float16* owF  = (_Float16*)p;  p += owF_b;
    _Float16* qkvF = (_Float16*)p;  p += qkvF_b;
    _Float16* ctxF = (_Float16*)p;  p += ctxF_b;

    float* out = (float*)d_out;
    dim3 blk(256);

    // fused fp32 -> fp16 converts (one launch for hs, pw, ow)
    {
        int nA = T * EMBED / 4;
        int nB = 3 * EMBED * EMBED / 4;
        int nC = EMBED * EMBED / 4;
        int total = nA + nB + nC;
        cvt3_f32_f16<<<(total + 255) / 256, blk, 0, stream>>>(
            hs, hsF, nA, pw, pwF, nB, ow, owF, nC);
    }

    // 1) QKV projection -> fp16 qkv   (gx=24, nwg=1152, %8==0)
    {
        int gx = (3 * EMBED) / 128;
        int nwg = gx * ((T + 127) / 128);
        gemm_m97<true><<<nwg, blk, 0, stream>>>(hsF, pwF, pb,
                                                (float*)nullptr, qkvF,
                                                T, 3 * EMBED, EMBED, gx);
    }

    // 2) attention -> fp16 ctx  (QBLK=64; nwg = 16 * maxTiles, %8==0)
    {
        int maxTiles = T / 64 + B;
        int nwg = NHEAD * maxTiles;
        attn_mfma<<<nwg, blk, 0, stream>>>(qkvF, cu, ctxF, B, maxTiles);
    }

    // 3) output projection -> fp32 out  (gx=8, nwg=384, %8==0)
    {
        int gx = EMBED / 128;
        int nwg = gx * ((T + 127) / 128);
        gemm_m97<false><<<nwg, blk, 0, stream>>>(ctxF, owF, ob,
                                                 out, (_Float16*)nullptr,
                                                 T, EMBED, EMBED, gx);
    }
}